// Round 4
// baseline (539.185 us; speedup 1.0000x reference)
//
#include <hip/hip_runtime.h>
#include <math.h>

#define NTOK  32768   // B*T
#define DDIM  2048
#define NEXP  64
#define TOPK  8
#define GAP_THR  1e-4f   // absolute logit-gap contested threshold
#define LIST_CAP 16384

// Workspace layout:
//   [0,16)          : cnt
//   [1024, 1024+512K): W fragments, bf16 hi/lo, MFMA B-frag order
//   after           : contested-token list (LIST_CAP ints)
#define WFRAG_OFF  1024
#define WFRAG_SZ   (64 * 4 * 2048)          // bytes: 64 ksteps x 4 egroups x 2KB
#define LIST_OFF   (WFRAG_OFF + WFRAG_SZ)

#define NKS   64      // k-steps of 32 (full K per block)
#define TOKB  128     // tokens per block

typedef __attribute__((ext_vector_type(8))) short s8_t;   // 8 bf16 (4 VGPR)
typedef __attribute__((ext_vector_type(4))) float f4_t;   // MFMA C/D
typedef __attribute__((ext_vector_type(4))) unsigned int u4_t;

typedef const __attribute__((address_space(1))) unsigned int* as1p;
typedef __attribute__((address_space(3))) unsigned int* as3p;

// async global->LDS, 16B per lane; LDS dest = uniform base + lane*16
__device__ __forceinline__ void gl2lds16(const void* g, void* l) {
  __builtin_amdgcn_global_load_lds((as1p)g, (as3p)l, 16, 0, 0);
}

// round-to-nearest-even f32 -> bf16 bits
__device__ __forceinline__ unsigned short f2bf(float f) {
  const unsigned u = __builtin_bit_cast(unsigned, f);
  const unsigned r = u + 0x7FFFu + ((u >> 16) & 1u);
  return (unsigned short)(r >> 16);
}

// split a pair of f32 into packed bf16 {hi,lo}: hi = RNE, lo = truncated
// residual. Dropped Xl*Wl + lo-trunc error ~2^-17 per term -> logit RMS
// error ~8e-6, 12x under GAP_THR (contested tokens go to the f64 pass).
struct bfpair { unsigned hi, lo; };
__device__ __forceinline__ bfpair split2(float a, float b) {
  const unsigned ua = __builtin_bit_cast(unsigned, a);
  const unsigned ub = __builtin_bit_cast(unsigned, b);
  const unsigned ra = ua + 0x7FFFu + ((ua >> 16) & 1u);
  const unsigned rb = ub + 0x7FFFu + ((ub >> 16) & 1u);
  bfpair r;
  r.hi = (ra >> 16) | (rb & 0xFFFF0000u);
  const float fa = a - __builtin_bit_cast(float, ra & 0xFFFF0000u);
  const float fb = b - __builtin_bit_cast(float, rb & 0xFFFF0000u);
  r.lo = (__builtin_bit_cast(unsigned, fa) >> 16) |
         (__builtin_bit_cast(unsigned, fb) & 0xFFFF0000u);
  return r;
}

// ---------------- W preprocessing: fp32 -> bf16 hi/lo fragments ------------
__global__ void wprep(const float* __restrict__ w, unsigned short* __restrict__ wf,
                      int* __restrict__ cnt) {
  if (blockIdx.x == 0 && threadIdx.x == 0) cnt[0] = 0;
  const int ks   = blockIdx.x;           // 0..63  (K step of 32)
  const int eg   = threadIdx.x >> 6;     // 0..3   (expert group of 16)
  const int lane = threadIdx.x & 63;
  const int kb   = ks * 32 + ((lane >> 4) << 3);
  const int e    = (eg << 4) + (lane & 15);
  s8_t h, l;
#pragma unroll
  for (int j = 0; j < 8; ++j) {
    const float v = w[(size_t)(kb + j) * NEXP + e];
    const unsigned short hb = f2bf(v);
    const float hf = __builtin_bit_cast(float, (unsigned)hb << 16);
    h[j] = (short)hb;
    l[j] = (short)f2bf(v - hf);
  }
  unsigned short* base = wf + (size_t)(ks * 4 + eg) * 1024 + lane * 8;
  *(s8_t*)(base)       = h;
  *(s8_t*)(base + 512) = l;
}

// ---------------- main pass: line-coalesced staging, depth-2 ring ----------
// 128 tok/block, 8 waves x 16 tok, full K. Per chunk (1 kstep): x 16KB
// (2 instr/wave, 8 rows x 128B fully-coalesced, source pre-swizzled
// slot^=row&7 so LDS stays linear) + W 8KB (1 instr/wave, linear).
// 3 loads/wave/chunk -> s_waitcnt vmcnt(3) keeps next chunk in flight.
__global__ __launch_bounds__(512, 2) void router_main(
    const float* __restrict__ x, const unsigned short* __restrict__ wfg,
    float* __restrict__ out, int* __restrict__ cnt, int* __restrict__ list) {
  __shared__ union __align__(16) {
    char ring[2][24 * 1024];     // [slot][ x 16KB | W 8KB ]
    float ll[TOKB * 68];         // epilogue transpose tile (34.8KB, aliased)
  } u;

  const int tid  = threadIdx.x;
  const int lane = tid & 63;
  const int wave = tid >> 6;      // 0..7
  const int col  = lane & 15;     // A row (token) / D col (expert lo)
  const int kgrp = lane >> 4;     // k-octet group
  const int wtok = blockIdx.x * TOKB + wave * 16;

  f4_t acc[4];
#pragma unroll
  for (int eg = 0; eg < 4; ++eg) acc[eg] = (f4_t){0.f, 0.f, 0.f, 0.f};

  // --- staging lane map: row = lane>>3 (8 consecutive rows x 128B runs),
  //     slot = lane&7, source slot pre-swizzled by ^row (rule 21).
  const int r8l = lane >> 3;      // 0..7
  const int s8l = lane & 7;       // 16B slot within the row's 128B
  const float* gx0 = x + (size_t)(wtok + r8l) * DDIM + ((s8l ^ r8l) << 2);
  const float* gx1 = gx0 + (size_t)8 * DDIM;
  const char*  gwb = (const char*)wfg + wave * 1024 + lane * 16;

  auto issue = [&](int c) {
    const int s = c & 1;
    char* xb = u.ring[s] + wave * 2048;
    gl2lds16(gx0 + c * 32, xb);           // rows 0-7 of wave tile
    gl2lds16(gx1 + c * 32, xb + 1024);    // rows 8-15
    gl2lds16(gwb + (size_t)c * 8192, u.ring[s] + 16384 + wave * 1024);
  };

  // compute one k-step from ring slot of chunk c (12 MFMA)
  auto compute = [&](int c) {
    const int s = c & 1;
    const char* lxb = u.ring[s] + wave * 2048;
    const char* lwb = u.ring[s] + 16384;
    // read back lane (col,kgrp)'s 8 floats; phys slot = granule ^ (row&7)
    const int q  = (col >> 3) * 1024 + (col & 7) * 128;
    const float4 v0 = *(const float4*)(lxb + q + (((2 * kgrp)     ^ (col & 7)) << 4));
    const float4 v1 = *(const float4*)(lxb + q + (((2 * kgrp + 1) ^ (col & 7)) << 4));
    const bfpair p0 = split2(v0.x, v0.y);
    const bfpair p1 = split2(v0.z, v0.w);
    const bfpair p2 = split2(v1.x, v1.y);
    const bfpair p3 = split2(v1.z, v1.w);
    const u4_t uh = {p0.hi, p1.hi, p2.hi, p3.hi};
    const u4_t ul = {p0.lo, p1.lo, p2.lo, p3.lo};
    const s8_t ah = __builtin_bit_cast(s8_t, uh);
    const s8_t al = __builtin_bit_cast(s8_t, ul);
#pragma unroll
    for (int eg = 0; eg < 4; ++eg) {
      const s8_t bh = *(const s8_t*)(lwb + eg * 2048 + lane * 16);
      const s8_t bl = *(const s8_t*)(lwb + eg * 2048 + 1024 + lane * 16);
      acc[eg] = __builtin_amdgcn_mfma_f32_16x16x32_bf16(ah, bh, acc[eg], 0, 0, 0);
      acc[eg] = __builtin_amdgcn_mfma_f32_16x16x32_bf16(al, bh, acc[eg], 0, 0, 0);
      acc[eg] = __builtin_amdgcn_mfma_f32_16x16x32_bf16(ah, bl, acc[eg], 0, 0, 0);
    }
  };

  issue(0);   // prologue: chunk 0 in flight (3 loads)

#pragma unroll 1
  for (int c = 0; c < NKS - 1; ++c) {
    issue(c + 1);
    // chunk c's 3 loads done; chunk c+1's 3 stay in flight (never drain to 0)
    asm volatile("s_waitcnt vmcnt(3)" ::: "memory");
    __builtin_amdgcn_s_barrier();
    asm volatile("" ::: "memory");   // no LDS reads hoisted above the barrier
    compute(c);
    asm volatile("" ::: "memory");   // no LDS reads sunk below the barrier
    __builtin_amdgcn_s_barrier();
  }
  asm volatile("s_waitcnt vmcnt(0)" ::: "memory");
  __builtin_amdgcn_s_barrier();
  asm volatile("" ::: "memory");
  compute(NKS - 1);
  __syncthreads();   // all computes done before ll (aliases ring) is written

  // D layout (HW-measured m89/m91): col = lane&15 (expert), row = kgrp*4+r
  // (token). Transpose through LDS (stride 68) so the epilogue runs
  // lane=expert.
#pragma unroll
  for (int eg = 0; eg < 4; ++eg)
#pragma unroll
    for (int r = 0; r < 4; ++r)
      u.ll[(wave * 16 + kgrp * 4 + r) * 68 + eg * 16 + col] = acc[eg][r];
  __syncthreads();

  float* out_w = out;                          // (NTOK, 8) weights
  float* out_i = out + (size_t)NTOK * TOPK;    // (NTOK, 8) indices as float

#pragma unroll 1
  for (int t = 0; t < 16; ++t) {
    const int row = wave * 16 + t;
    const int tok = blockIdx.x * TOKB + row;
    const float v = u.ll[row * 68 + lane];  // logit for expert `lane`

    // softmax over 64 experts
    float m = v;
#pragma unroll
    for (int off = 32; off; off >>= 1) m = fmaxf(m, __shfl_xor(m, off));
    const float ex = __expf(v - m);
    float s = ex;
#pragma unroll
    for (int off = 32; off; off >>= 1) s += __shfl_xor(s, off);
    float pw = ex / s;   // prob (selection key, knocked out as picked)
    float lw = v;        // logit (rides along for the gap check)
    int   ii = lane;

    // top-9; tie -> lower index (rank 9 only feeds the gap check)
    float selp[TOPK + 1];
    float sell[TOPK + 1];
    int   seli[TOPK + 1];
#pragma unroll
    for (int r = 0; r < TOPK + 1; ++r) {
      float bp = pw; float bl = lw; int bi = ii;
#pragma unroll
      for (int off = 32; off; off >>= 1) {
        const float op = __shfl_xor(bp, off);
        const float ol = __shfl_xor(bl, off);
        const int   oi = __shfl_xor(bi, off);
        const bool take = (op > bp) || (op == bp && oi < bi);
        bp = take ? op : bp;
        bl = take ? ol : bl;
        bi = take ? oi : bi;
      }
      selp[r] = bp; sell[r] = bl; seli[r] = bi;
      if (lane == bi) pw = -__builtin_inff();
    }

    bool contested = false;
#pragma unroll
    for (int k = 0; k < TOPK; ++k)
      contested |= (sell[k] - sell[k + 1]) <= GAP_THR;

    // commit fp32 result for every token (contested ones overwritten later)
    const float mm = selp[0];
    float ssum = 0.0f;
#pragma unroll
    for (int k = 0; k < TOPK; ++k) ssum += __expf(selp[k] - mm);
    float myv = selp[0];
    int   myi = seli[0];
#pragma unroll
    for (int k = 1; k < TOPK; ++k)
      if (lane == k) { myv = selp[k]; myi = seli[k]; }
    if (lane < TOPK) {
      out_w[(size_t)tok * TOPK + lane] = __expf(myv - mm) / ssum;
      out_i[(size_t)tok * TOPK + lane] = (float)myi;
    }

    if (contested && lane == 0) {
      const int idx = atomicAdd(cnt, 1);
      if (idx < LIST_CAP) list[idx] = tok;
    }
  }
}

// ---------------- fix pass: f64 recompute of contested tokens --------------
__global__ __launch_bounds__(256, 1) void router_fix(
    const float* __restrict__ x, const float* __restrict__ w,
    float* __restrict__ out, const int* __restrict__ cnt,
    const int* __restrict__ list) {
  const int lane = threadIdx.x & 63;
  const int wave = threadIdx.x >> 6;
  const int gw   = blockIdx.x * 4 + wave;
  const int NW   = gridDim.x * 4;

  int n = cnt[0];
  if (n > LIST_CAP) n = LIST_CAP;

  float* out_w = out;
  float* out_i = out + (size_t)NTOK * TOPK;

  for (int i = gw; i < n; i += NW) {
    const int tok = list[i];
    const float* xr = x + (size_t)tok * DDIM;
    double a0 = 0.0, a1 = 0.0, a2 = 0.0, a3 = 0.0;  // 4 indep chains
#pragma unroll 4
    for (int d4 = 0; d4 < DDIM / 4; ++d4) {
      const float4 xv = *(const float4*)(xr + d4 * 4);
      const int r = d4 * 4;
      a0 = fma((double)xv.x, (double)w[(r + 0) * NEXP + lane], a0);
      a1 = fma((double)xv.y, (double)w[(r + 1) * NEXP + lane], a1);
      a2 = fma((double)xv.z, (double)w[(r + 2) * NEXP + lane], a2);
      a3 = fma((double)xv.w, (double)w[(r + 3) * NEXP + lane], a3);
    }
    const double a = (a0 + a1) + (a2 + a3);

    double dm = a;
#pragma unroll
    for (int off = 32; off; off >>= 1) dm = fmax(dm, __shfl_xor(dm, off));
    const double dex = exp(a - dm);
    double ds = dex;
#pragma unroll
    for (int off = 32; off; off >>= 1) ds += __shfl_xor(ds, off);
    double dpv = dex / ds;

    double dselv[TOPK];
    int    dseli[TOPK];
#pragma unroll
    for (int r = 0; r < TOPK; ++r) {
      double bv = dpv;
      int    bi = lane;
#pragma unroll
      for (int off = 32; off; off >>= 1) {
        const double ov = __shfl_xor(bv, off);
        const int    oi = __shfl_xor(bi, off);
        const bool take = (ov > bv) || (ov == bv && oi < bi);
        bv = take ? ov : bv;
        bi = take ? oi : bi;
      }
      dselv[r] = bv;
      dseli[r] = bi;
      if (lane == bi) dpv = -1.0e300;
    }
    const double dmm = dselv[0];
    double dssum = 0.0;
#pragma unroll
    for (int k = 0; k < TOPK; ++k) dssum += exp(dselv[k] - dmm);
    double myv = dselv[0];
    int    myi = dseli[0];
#pragma unroll
    for (int k = 1; k < TOPK; ++k)
      if (lane == k) { myv = dselv[k]; myi = dseli[k]; }
    if (lane < TOPK) {
      out_w[(size_t)tok * TOPK + lane] = (float)(exp(myv - dmm) / dssum);
      out_i[(size_t)tok * TOPK + lane] = (float)myi;
    }
  }
}

extern "C" void kernel_launch(void* const* d_in, const int* in_sizes, int n_in,
                              void* d_out, int out_size, void* d_ws, size_t ws_size,
                              hipStream_t stream) {
  const float* x = (const float*)d_in[0];
  const float* w = (const float*)d_in[1];
  int* cnt = (int*)d_ws;
  unsigned short* wfrag = (unsigned short*)((char*)d_ws + WFRAG_OFF);
  int* list = (int*)((char*)d_ws + LIST_OFF);

  wprep<<<dim3(64), dim3(256), 0, stream>>>(w, wfrag, cnt);
  router_main<<<dim3(NTOK / TOKB), dim3(512), 0, stream>>>(
      x, wfrag, (float*)d_out, cnt, list);
  router_fix<<<dim3(256), dim3(256), 0, stream>>>(
      x, w, (float*)d_out, cnt, list);
}